// Round 8
// baseline (178.554 us; speedup 1.0000x reference)
//
#include <hip/hip_runtime.h>

#define BB 8
#define SS 2048
#define DD 128
#define SEG ((size_t)BB * SS * DD)   // elements per partial segment

typedef _Float16 f16;
typedef _Float16 f16x2 __attribute__((ext_vector_type(2)));
typedef __fp16 h16x2 __attribute__((ext_vector_type(2)));
typedef _Float16 f16x8 __attribute__((ext_vector_type(8)));
typedef float f32x4 __attribute__((ext_vector_type(4)));

// Vt LDS swizzle: spreads banks for BOTH staging writes and PV reads.
#define SWV(d) ((((d) & 7) ^ (((d) >> 3) & 7)) << 3)

#define DEFER_THR 4.0f   // exp2-domain defer-max threshold: P <= 16, f16-safe

static __device__ __forceinline__ float fast_exp2(float x) {
#if __has_builtin(__builtin_amdgcn_exp2f)
    return __builtin_amdgcn_exp2f(x);
#else
    return exp2f(x);
#endif
}

static __device__ __forceinline__ f16x2 cvt_pk(float a, float b) {
    h16x2 r = __builtin_amdgcn_cvt_pkrtz(a, b);
    return __builtin_bit_cast(f16x2, r);
}

// pack 4 f32 -> 4 f16 (RTZ) as uint2 for one b64 LDS write
static __device__ __forceinline__ uint2 pack4(f32x4 v) {
    f16x2 lo = cvt_pk(v[0], v[1]);
    f16x2 hi = cvt_pk(v[2], v[3]);
    uint2 u;
    u.x = __builtin_bit_cast(unsigned int, lo);
    u.y = __builtin_bit_cast(unsigned int, hi);
    return u;
}

// ---------------------------------------------------------------------------
// Flash attention forward, causal. f16 MFMA 16x16x32, fp32 softmax/accum.
// 512 threads = 8 waves; QBLK=128 (wave w owns rows qb*128 + w*16 .. +15).
// Grid = 8 batches x 16 qblocks x NS = 512 blocks @ NS=4 -> EXACTLY 2
// blocks/CU, all resident (LDS 80KB x 2 = 160KB, VGPR <= 128 via bounds).
// KV tiles of 64 keys, double-buffered; one barrier per tile.
// Waves 0-3 skip the final (fully-masked) tile via the `active` guard.
// K  LDS: [2][64][128], el = row*128 + (col ^ ((row&7)<<3))
// Vt LDS: [2][128][64], el = d*64   + (key ^ SWV(d))
// P  LDS: per-wave [16][64], el = row*64 + (col ^ ((row&7)<<3))
// ---------------------------------------------------------------------------
template <int NS>
__global__ __launch_bounds__(512, 4)
void attn_fwd(const float* __restrict__ Qg, const float* __restrict__ Kg,
              const float* __restrict__ Vg, float* __restrict__ Og,
              f16* __restrict__ Opf, float2* __restrict__ mlb)
{
    __shared__ __align__(16) f16 Kl[2][64 * 128];
    __shared__ __align__(16) f16 Vt[2][128 * 64];
    __shared__ __align__(16) f16 Pl[8][16 * 64];

    const int tid  = threadIdx.x;
    const int lane = tid & 63;
    const int w    = tid >> 6;    // wave 0..7
    const int c_   = lane & 15;   // key col (QK^T) / d col (PV out)
    const int g    = lane >> 4;

    // block decode: batch -> XCD; qb descending (LPT); split segment
    const int L   = blockIdx.x;
    const int bb  = L & 7;
    const int rem = L >> 3;
    const int qb  = 15 - (rem / NS);
    const int sg  = rem % NS;
    const int T   = 2 * qb + 2;
    const int t0  = (T * sg) / NS;
    const int t1  = (T * (sg + 1)) / NS;

    const int qrow0 = qb * 128 + w * 16;
    const int dt    = 2 * qb + (w >> 2);   // this wave's diagonal tile

    // Q fragments, pre-scaled by 1/sqrt(D) * log2(e)
    const float qs = 0.08838834764831845f * 1.4426950408889634f;
    f16x8 qf[4];
    {
        const float* qp = Qg + (size_t)(bb * SS + qrow0 + c_) * DD;
#pragma unroll
        for (int kk = 0; kk < 4; ++kk) {
            const int d0 = kk * 32 + g * 8;
            f32x4 a = *(const f32x4*)(qp + d0);
            f32x4 b = *(const f32x4*)(qp + d0 + 4);
            f16x8 q;
#pragma unroll
            for (int i = 0; i < 4; ++i) {
                q[i]     = (f16)(a[i] * qs);
                q[i + 4] = (f16)(b[i] * qs);
            }
            qf[kk] = q;
        }
    }

    f32x4 Oa[8];
#pragma unroll
    for (int i = 0; i < 8; ++i) Oa[i] = (f32x4){0.f, 0.f, 0.f, 0.f};
    float mrun[4] = {-1e30f, -1e30f, -1e30f, -1e30f};
    float lpart[4] = {0.f, 0.f, 0.f, 0.f};   // per-lane partial l

    f16* Pw = &Pl[w][0];

    // staging thread mappings (512 threads)
    const int krow  = tid >> 5;     // K: row = krow + 16j   (0..15)
    const int kc4   = tid & 31;     // K: col quad
    const int vkey4 = tid >> 5;     // V: key group of 4 (0..15)
    const int vq    = tid & 31;     // V: d quad (d = vq*4 + dd)

    f32x4 kreg[4], vreg[4];

#define LOADT(tt)                                                              \
    {                                                                          \
        const size_t gb = (size_t)(bb * SS + (tt) * 64) * DD;                  \
        _Pragma("unroll")                                                      \
        for (int j = 0; j < 4; ++j)                                            \
            kreg[j] = *(const f32x4*)(Kg + gb + (krow + 16 * j) * DD + kc4 * 4);\
        _Pragma("unroll")                                                      \
        for (int i = 0; i < 4; ++i)                                            \
            vreg[i] = *(const f32x4*)(Vg + gb + (vkey4 * 4 + i) * DD + vq * 4);\
    }

#define STAGE_K(pb_)                                                           \
    {                                                                          \
        _Pragma("unroll")                                                      \
        for (int j = 0; j < 4; ++j) {                                          \
            const int row = krow + 16 * j;                                     \
            const int el  = row * 128 + ((kc4 * 4) ^ ((row & 7) << 3));        \
            *(uint2*)&Kl[pb_][el] = pack4(kreg[j]);                            \
        }                                                                      \
    }

#define STAGE_V(pb_)                                                           \
    {                                                                          \
        _Pragma("unroll")                                                      \
        for (int dd = 0; dd < 4; ++dd) {                                       \
            const int d  = vq * 4 + dd;                                        \
            const int sw = SWV(d);                                             \
            f32x4 vv = {vreg[0][dd], vreg[1][dd], vreg[2][dd], vreg[3][dd]};   \
            const int el = d * 64 + ((vkey4 * 4) ^ sw);                        \
            *(uint2*)&Vt[pb_][el] = pack4(vv);                                 \
        }                                                                      \
    }

    if (t0 < t1) {
        // prologue: fill buf[t0&1] with tile t0; issue loads for t0+1
        LOADT(t0);
        STAGE_K(t0 & 1);
        STAGE_V(t0 & 1);
        if (t0 + 1 < t1) LOADT(t0 + 1);
        __syncthreads();

        for (int t = t0; t < t1; ++t) {
            const int pb = t & 1;
            const bool more   = (t + 1 < t1);
            const bool active = (t <= dt);
            const int kbase = t * 64;

            f32x4 s4[4];
            if (active) {
                // ---- QK^T from Kl[pb] ----
                __builtin_amdgcn_s_setprio(1);
#pragma unroll
                for (int nb = 0; nb < 4; ++nb) {
                    f32x4 acc = (f32x4){0.f, 0.f, 0.f, 0.f};
                    const int row = c_ + nb * 16;
                    const int sw  = (row & 7) << 3;
#pragma unroll
                    for (int kk = 0; kk < 4; ++kk) {
                        f16x8 kb = *(const f16x8*)&Kl[pb][row * 128 + ((kk * 32 + g * 8) ^ sw)];
                        acc = __builtin_amdgcn_mfma_f32_16x16x32_f16(qf[kk], kb, acc, 0, 0, 0);
                    }
                    s4[nb] = acc;
                }
                __builtin_amdgcn_s_setprio(0);
            }

            // ---- stage K(t+1) into other buffer (hides under softmax) ----
            if (more) STAGE_K(pb ^ 1);

            if (active) {
                // ---- causal mask (wave's diagonal tile only) ----
                if (t == dt) {
#pragma unroll
                    for (int nb = 0; nb < 4; ++nb)
#pragma unroll
                        for (int r = 0; r < 4; ++r) {
                            const int kj = kbase + nb * 16 + c_;
                            const int qi = qrow0 + g * 4 + r;
                            if (kj > qi) s4[nb][r] = -1e30f;
                        }
                }

                // ---- softmax: wave-max fast path, per-row slow path ----
                float wm = -1e30f;
#pragma unroll
                for (int nb = 0; nb < 4; ++nb) {
                    f32x4 v = s4[nb];
                    wm = fmaxf(wm, fmaxf(fmaxf(v[0], v[1]), fmaxf(v[2], v[3])));
                }
                wm = fmaxf(wm, __shfl_xor(wm, 1));
                wm = fmaxf(wm, __shfl_xor(wm, 2));
                wm = fmaxf(wm, __shfl_xor(wm, 4));
                wm = fmaxf(wm, __shfl_xor(wm, 8));
                wm = fmaxf(wm, __shfl_xor(wm, 16));
                wm = fmaxf(wm, __shfl_xor(wm, 32));
                float mrmin = fminf(fminf(mrun[0], mrun[1]), fminf(mrun[2], mrun[3]));

                if (!__all(wm - mrmin <= DEFER_THR)) {
                    float sc[4];
                    float scmin = 1.0f;
#pragma unroll
                    for (int r = 0; r < 4; ++r) {
                        float pm = fmaxf(fmaxf(s4[0][r], s4[1][r]),
                                         fmaxf(s4[2][r], s4[3][r]));
                        pm = fmaxf(pm, __shfl_xor(pm, 1));
                        pm = fmaxf(pm, __shfl_xor(pm, 2));
                        pm = fmaxf(pm, __shfl_xor(pm, 4));
                        pm = fmaxf(pm, __shfl_xor(pm, 8));
                        const bool keep = (pm - mrun[r] <= DEFER_THR);
                        sc[r] = keep ? 1.0f : fast_exp2(mrun[r] - pm);
                        if (!keep) mrun[r] = pm;
                        scmin = fminf(scmin, sc[r]);
                    }
                    if (scmin < 1.0f) {
#pragma unroll
                        for (int r = 0; r < 4; ++r) {
                            lpart[r] *= sc[r];
#pragma unroll
                            for (int dblk = 0; dblk < 8; ++dblk)
                                Oa[dblk][r] *= sc[r];
                        }
                    }
                }

                // ---- P = exp2(S - m), pack, write to LDS ----
#pragma unroll
                for (int nb = 0; nb < 4; ++nb) {
                    float pv[4];
#pragma unroll
                    for (int r = 0; r < 4; ++r) {
                        pv[r] = fast_exp2(s4[nb][r] - mrun[r]);
                        lpart[r] += pv[r];
                    }
                    f16x2 p01 = cvt_pk(pv[0], pv[1]);
                    f16x2 p23 = cvt_pk(pv[2], pv[3]);
#pragma unroll
                    for (int r = 0; r < 4; ++r) {
                        const int row = g * 4 + r;
                        const f16 hv = (r < 2) ? p01[r & 1] : p23[r & 1];
                        Pw[row * 64 + ((nb * 16 + c_) ^ ((row & 7) << 3))] = hv;
                    }
                }
            }

            // ---- stage V(t+1) into other buffer (hides under P/PV) ----
            if (more) STAGE_V(pb ^ 1);

            if (active) {
                // ---- PV: A = P, B = Vt[pb] ----
#pragma unroll
                for (int ks = 0; ks < 2; ++ks) {
                    f16x8 pa = *(const f16x8*)&Pw[c_ * 64 + ((ks * 32 + g * 8) ^ ((c_ & 7) << 3))];
                    __builtin_amdgcn_s_setprio(1);
#pragma unroll
                    for (int dblk = 0; dblk < 8; ++dblk) {
                        const int d  = dblk * 16 + c_;
                        f16x8 vb = *(const f16x8*)&Vt[pb][d * 64 + ((ks * 32 + g * 8) ^ SWV(d))];
                        Oa[dblk] = __builtin_amdgcn_mfma_f32_16x16x32_f16(pa, vb, Oa[dblk], 0, 0, 0);
                    }
                    __builtin_amdgcn_s_setprio(0);
                }
            }

            // ---- issue global loads for tile t+2 (regs now free) ----
            if (t + 2 < t1) LOADT(t + 2);
            if (more) __syncthreads();
        }
    }

    // ---- reduce deferred l across the 16 key-lanes ----
    float lrun[4];
#pragma unroll
    for (int r = 0; r < 4; ++r) {
        float v = lpart[r];
        v += __shfl_xor(v, 1);
        v += __shfl_xor(v, 2);
        v += __shfl_xor(v, 4);
        v += __shfl_xor(v, 8);
        lrun[r] = v;
    }

    // ---- epilogue ----
    if (NS == 1) {
#pragma unroll
        for (int r = 0; r < 4; ++r) {
            const int qrow = qrow0 + g * 4 + r;
            float* dst = Og + (size_t)(bb * SS + qrow) * DD + c_;
            const float inv = (lrun[r] > 0.f) ? 1.0f / lrun[r] : 0.f;
#pragma unroll
            for (int dblk = 0; dblk < 8; ++dblk)
                dst[dblk * 16] = Oa[dblk][r] * inv;
        }
    } else {
        // unnormalized f16 partial + (m, l)
        f16*    od  = Opf + (size_t)sg * SEG;
        float2* mld = mlb + (size_t)sg * BB * SS;
#pragma unroll
        for (int r = 0; r < 4; ++r) {
            const int qrow = qrow0 + g * 4 + r;
            f16* dst = od + (size_t)(bb * SS + qrow) * DD + c_;
#pragma unroll
            for (int dblk = 0; dblk < 8; ++dblk)
                dst[dblk * 16] = (f16)Oa[dblk][r];
            if (c_ == 0) mld[bb * SS + qrow] = make_float2(mrun[r], lrun[r]);
        }
    }
}

// ---------------------------------------------------------------------------
// Merge NS KV-split f16 partials: out = (sum Oi*ei) / (sum li*ei)
// Each thread handles 8 contiguous d-elements of one row.
// ---------------------------------------------------------------------------
template <int NS>
__global__ __launch_bounds__(256)
void merge_kernel(float* __restrict__ out, const f16* __restrict__ Opf,
                  const float2* __restrict__ mlb)
{
    const int idx = blockIdx.x * 256 + threadIdx.x;  // 8-elem units
    const int row = idx >> 4;                        // 16 units per row
    float2 ml[NS];
#pragma unroll
    for (int i = 0; i < NS; ++i) ml[i] = mlb[(size_t)i * BB * SS + row];
    float mm = ml[0].x;
#pragma unroll
    for (int i = 1; i < NS; ++i) mm = fmaxf(mm, ml[i].x);
    float e[NS], den = 0.f;
#pragma unroll
    for (int i = 0; i < NS; ++i) {
        e[i] = fast_exp2(ml[i].x - mm);
        den += ml[i].y * e[i];
    }
    const float inv = 1.0f / den;

    float acc[8] = {0.f, 0.f, 0.f, 0.f, 0.f, 0.f, 0.f, 0.f};
#pragma unroll
    for (int i = 0; i < NS; ++i) {
        f16x8 v = *(const f16x8*)(Opf + (size_t)i * SEG + (size_t)idx * 8);
#pragma unroll
        for (int j = 0; j < 8; ++j) acc[j] += (float)v[j] * e[i];
    }
    float4 o0, o1;
    o0.x = acc[0] * inv; o0.y = acc[1] * inv; o0.z = acc[2] * inv; o0.w = acc[3] * inv;
    o1.x = acc[4] * inv; o1.y = acc[5] * inv; o1.z = acc[6] * inv; o1.w = acc[7] * inv;
    float4* dst = (float4*)(out + (size_t)idx * 8);
    dst[0] = o0;
    dst[1] = o1;
}

extern "C" void kernel_launch(void* const* d_in, const int* in_sizes, int n_in,
                              void* d_out, int out_size, void* d_ws, size_t ws_size,
                              hipStream_t stream)
{
    const float* Q = (const float*)d_in[0];
    const float* K = (const float*)d_in[1];
    const float* V = (const float*)d_in[2];
    float* out = (float*)d_out;

    const size_t OPB = SEG * sizeof(f16);                 // 4 MB per segment
    const size_t MLB = (size_t)BB * SS * sizeof(float2);  // 128 KB per segment
    const int mergeGrid = (int)(SEG / 8 / 256);           // 1024

    const size_t need4 = 4 * OPB + 4 * MLB;

    if (ws_size >= need4) {
        f16*    Opf = (f16*)d_ws;
        float2* mlb = (float2*)((char*)d_ws + 4 * OPB);
        hipLaunchKernelGGL((attn_fwd<4>), dim3(8 * 16 * 4), dim3(512), 0, stream,
                           Q, K, V, out, Opf, mlb);
        hipLaunchKernelGGL((merge_kernel<4>), dim3(mergeGrid), dim3(256), 0, stream,
                           out, Opf, mlb);
    } else {
        hipLaunchKernelGGL((attn_fwd<1>), dim3(8 * 16), dim3(512), 0, stream,
                           Q, K, V, out, (f16*)nullptr, (float2*)nullptr);
    }
}

// Round 9
// 103.539 us; speedup vs baseline: 1.7245x; 1.7245x over previous
//
#include <hip/hip_runtime.h>

#define BB 8
#define SS 2048
#define DD 128
#define SEG ((size_t)BB * SS * DD)   // elements per partial segment

typedef _Float16 f16;
typedef _Float16 f16x2 __attribute__((ext_vector_type(2)));
typedef __fp16 h16x2 __attribute__((ext_vector_type(2)));
typedef _Float16 f16x8 __attribute__((ext_vector_type(8)));
typedef float f32x4 __attribute__((ext_vector_type(4)));

// Vt LDS swizzle: spreads banks for BOTH staging writes and PV reads.
#define SWV(d) ((((d) & 7) ^ (((d) >> 3) & 7)) << 3)

#define DEFER_THR 4.0f   // exp2-domain defer-max threshold: P <= 16, f16-safe

static __device__ __forceinline__ float fast_exp2(float x) {
#if __has_builtin(__builtin_amdgcn_exp2f)
    return __builtin_amdgcn_exp2f(x);
#else
    return exp2f(x);
#endif
}

static __device__ __forceinline__ f16x2 cvt_pk(float a, float b) {
    h16x2 r = __builtin_amdgcn_cvt_pkrtz(a, b);
    return __builtin_bit_cast(f16x2, r);
}

// pack 4 f32 -> 4 f16 (RTZ) as uint2 for one b64 LDS write
static __device__ __forceinline__ uint2 pack4(f32x4 v) {
    f16x2 lo = cvt_pk(v[0], v[1]);
    f16x2 hi = cvt_pk(v[2], v[3]);
    uint2 u;
    u.x = __builtin_bit_cast(unsigned int, lo);
    u.y = __builtin_bit_cast(unsigned int, hi);
    return u;
}

// ---------------------------------------------------------------------------
// Flash attention forward, causal. f16 MFMA 16x16x32, fp32 softmax/accum.
// 512 threads = 8 waves; QBLK=128 (wave w owns rows qb*128 + w*16 .. +15).
// Grid = 8 batches x 16 qblocks x NS = 512 blocks @ NS=4 -> EXACTLY 2
// blocks/CU, all resident. LDS 80KB x 2 = 160KB/CU.
// __launch_bounds__(512, 2): 2 BLOCKS/CU (HIP treats arg2 CUDA-style as min
// blocks/MP -> 16 waves/CU -> 128-VGPR cap; R8's (512,4) forced 64 VGPR and
// spilled: FETCH 12->119MB).
// KV tiles of 64 keys, double-buffered; one barrier per tile.
// Waves 0-3 skip the final (fully-masked) tile via the `active` guard.
// K  LDS: [2][64][128], el = row*128 + (col ^ ((row&7)<<3))
// Vt LDS: [2][128][64], el = d*64   + (key ^ SWV(d))
// P  LDS: per-wave [16][64], el = row*64 + (col ^ ((row&7)<<3))
// ---------------------------------------------------------------------------
template <int NS>
__global__ __launch_bounds__(512, 2)
void attn_fwd(const float* __restrict__ Qg, const float* __restrict__ Kg,
              const float* __restrict__ Vg, float* __restrict__ Og,
              f16* __restrict__ Opf, float2* __restrict__ mlb)
{
    __shared__ __align__(16) f16 Kl[2][64 * 128];
    __shared__ __align__(16) f16 Vt[2][128 * 64];
    __shared__ __align__(16) f16 Pl[8][16 * 64];

    const int tid  = threadIdx.x;
    const int lane = tid & 63;
    const int w    = tid >> 6;    // wave 0..7
    const int c_   = lane & 15;   // key col (QK^T) / d col (PV out)
    const int g    = lane >> 4;

    // block decode: batch -> XCD; qb descending (LPT); split segment
    const int L   = blockIdx.x;
    const int bb  = L & 7;
    const int rem = L >> 3;
    const int qb  = 15 - (rem / NS);
    const int sg  = rem % NS;
    const int T   = 2 * qb + 2;
    const int t0  = (T * sg) / NS;
    const int t1  = (T * (sg + 1)) / NS;

    const int qrow0 = qb * 128 + w * 16;
    const int dt    = 2 * qb + (w >> 2);   // this wave's diagonal tile

    // Q fragments, pre-scaled by 1/sqrt(D) * log2(e)
    const float qs = 0.08838834764831845f * 1.4426950408889634f;
    f16x8 qf[4];
    {
        const float* qp = Qg + (size_t)(bb * SS + qrow0 + c_) * DD;
#pragma unroll
        for (int kk = 0; kk < 4; ++kk) {
            const int d0 = kk * 32 + g * 8;
            f32x4 a = *(const f32x4*)(qp + d0);
            f32x4 b = *(const f32x4*)(qp + d0 + 4);
            f16x8 q;
#pragma unroll
            for (int i = 0; i < 4; ++i) {
                q[i]     = (f16)(a[i] * qs);
                q[i + 4] = (f16)(b[i] * qs);
            }
            qf[kk] = q;
        }
    }

    f32x4 Oa[8];
#pragma unroll
    for (int i = 0; i < 8; ++i) Oa[i] = (f32x4){0.f, 0.f, 0.f, 0.f};
    float mrun[4] = {-1e30f, -1e30f, -1e30f, -1e30f};
    float lpart[4] = {0.f, 0.f, 0.f, 0.f};   // per-lane partial l

    f16* Pw = &Pl[w][0];

    // staging thread mappings (512 threads)
    const int krow  = tid >> 5;     // K: row = krow + 16j   (0..15)
    const int kc4   = tid & 31;     // K: col quad
    const int vkey4 = tid >> 5;     // V: key group of 4 (0..15)
    const int vq    = tid & 31;     // V: d quad (d = vq*4 + dd)

    f32x4 kreg[4], vreg[4];

#define LOADT(tt)                                                              \
    {                                                                          \
        const size_t gb = (size_t)(bb * SS + (tt) * 64) * DD;                  \
        _Pragma("unroll")                                                      \
        for (int j = 0; j < 4; ++j)                                            \
            kreg[j] = *(const f32x4*)(Kg + gb + (krow + 16 * j) * DD + kc4 * 4);\
        _Pragma("unroll")                                                      \
        for (int i = 0; i < 4; ++i)                                            \
            vreg[i] = *(const f32x4*)(Vg + gb + (vkey4 * 4 + i) * DD + vq * 4);\
    }

#define STAGE_K(pb_)                                                           \
    {                                                                          \
        _Pragma("unroll")                                                      \
        for (int j = 0; j < 4; ++j) {                                          \
            const int row = krow + 16 * j;                                     \
            const int el  = row * 128 + ((kc4 * 4) ^ ((row & 7) << 3));        \
            *(uint2*)&Kl[pb_][el] = pack4(kreg[j]);                            \
        }                                                                      \
    }

#define STAGE_V(pb_)                                                           \
    {                                                                          \
        _Pragma("unroll")                                                      \
        for (int dd = 0; dd < 4; ++dd) {                                       \
            const int d  = vq * 4 + dd;                                        \
            const int sw = SWV(d);                                             \
            f32x4 vv = {vreg[0][dd], vreg[1][dd], vreg[2][dd], vreg[3][dd]};   \
            const int el = d * 64 + ((vkey4 * 4) ^ sw);                        \
            *(uint2*)&Vt[pb_][el] = pack4(vv);                                 \
        }                                                                      \
    }

    if (t0 < t1) {
        // prologue: fill buf[t0&1] with tile t0; issue loads for t0+1
        LOADT(t0);
        STAGE_K(t0 & 1);
        STAGE_V(t0 & 1);
        if (t0 + 1 < t1) LOADT(t0 + 1);
        __syncthreads();

        for (int t = t0; t < t1; ++t) {
            const int pb = t & 1;
            const bool more   = (t + 1 < t1);
            const bool active = (t <= dt);
            const int kbase = t * 64;

            f32x4 s4[4];
            if (active) {
                // ---- QK^T from Kl[pb] ----
                __builtin_amdgcn_s_setprio(1);
#pragma unroll
                for (int nb = 0; nb < 4; ++nb) {
                    f32x4 acc = (f32x4){0.f, 0.f, 0.f, 0.f};
                    const int row = c_ + nb * 16;
                    const int sw  = (row & 7) << 3;
#pragma unroll
                    for (int kk = 0; kk < 4; ++kk) {
                        f16x8 kb = *(const f16x8*)&Kl[pb][row * 128 + ((kk * 32 + g * 8) ^ sw)];
                        acc = __builtin_amdgcn_mfma_f32_16x16x32_f16(qf[kk], kb, acc, 0, 0, 0);
                    }
                    s4[nb] = acc;
                }
                __builtin_amdgcn_s_setprio(0);
            }

            // ---- stage K(t+1) into other buffer (hides under softmax) ----
            if (more) STAGE_K(pb ^ 1);

            if (active) {
                // ---- causal mask (wave's diagonal tile only) ----
                if (t == dt) {
#pragma unroll
                    for (int nb = 0; nb < 4; ++nb)
#pragma unroll
                        for (int r = 0; r < 4; ++r) {
                            const int kj = kbase + nb * 16 + c_;
                            const int qi = qrow0 + g * 4 + r;
                            if (kj > qi) s4[nb][r] = -1e30f;
                        }
                }

                // ---- softmax: wave-max fast path, per-row slow path ----
                float wm = -1e30f;
#pragma unroll
                for (int nb = 0; nb < 4; ++nb) {
                    f32x4 v = s4[nb];
                    wm = fmaxf(wm, fmaxf(fmaxf(v[0], v[1]), fmaxf(v[2], v[3])));
                }
                wm = fmaxf(wm, __shfl_xor(wm, 1));
                wm = fmaxf(wm, __shfl_xor(wm, 2));
                wm = fmaxf(wm, __shfl_xor(wm, 4));
                wm = fmaxf(wm, __shfl_xor(wm, 8));
                wm = fmaxf(wm, __shfl_xor(wm, 16));
                wm = fmaxf(wm, __shfl_xor(wm, 32));
                float mrmin = fminf(fminf(mrun[0], mrun[1]), fminf(mrun[2], mrun[3]));

                if (!__all(wm - mrmin <= DEFER_THR)) {
                    float sc[4];
                    float scmin = 1.0f;
#pragma unroll
                    for (int r = 0; r < 4; ++r) {
                        float pm = fmaxf(fmaxf(s4[0][r], s4[1][r]),
                                         fmaxf(s4[2][r], s4[3][r]));
                        pm = fmaxf(pm, __shfl_xor(pm, 1));
                        pm = fmaxf(pm, __shfl_xor(pm, 2));
                        pm = fmaxf(pm, __shfl_xor(pm, 4));
                        pm = fmaxf(pm, __shfl_xor(pm, 8));
                        const bool keep = (pm - mrun[r] <= DEFER_THR);
                        sc[r] = keep ? 1.0f : fast_exp2(mrun[r] - pm);
                        if (!keep) mrun[r] = pm;
                        scmin = fminf(scmin, sc[r]);
                    }
                    if (scmin < 1.0f) {
#pragma unroll
                        for (int r = 0; r < 4; ++r) {
                            lpart[r] *= sc[r];
#pragma unroll
                            for (int dblk = 0; dblk < 8; ++dblk)
                                Oa[dblk][r] *= sc[r];
                        }
                    }
                }

                // ---- P = exp2(S - m), pack, write to LDS ----
#pragma unroll
                for (int nb = 0; nb < 4; ++nb) {
                    float pv[4];
#pragma unroll
                    for (int r = 0; r < 4; ++r) {
                        pv[r] = fast_exp2(s4[nb][r] - mrun[r]);
                        lpart[r] += pv[r];
                    }
                    f16x2 p01 = cvt_pk(pv[0], pv[1]);
                    f16x2 p23 = cvt_pk(pv[2], pv[3]);
#pragma unroll
                    for (int r = 0; r < 4; ++r) {
                        const int row = g * 4 + r;
                        const f16 hv = (r < 2) ? p01[r & 1] : p23[r & 1];
                        Pw[row * 64 + ((nb * 16 + c_) ^ ((row & 7) << 3))] = hv;
                    }
                }
            }

            // ---- stage V(t+1) into other buffer (hides under P/PV) ----
            if (more) STAGE_V(pb ^ 1);

            if (active) {
                // ---- PV: A = P, B = Vt[pb] ----
#pragma unroll
                for (int ks = 0; ks < 2; ++ks) {
                    f16x8 pa = *(const f16x8*)&Pw[c_ * 64 + ((ks * 32 + g * 8) ^ ((c_ & 7) << 3))];
                    __builtin_amdgcn_s_setprio(1);
#pragma unroll
                    for (int dblk = 0; dblk < 8; ++dblk) {
                        const int d  = dblk * 16 + c_;
                        f16x8 vb = *(const f16x8*)&Vt[pb][d * 64 + ((ks * 32 + g * 8) ^ SWV(d))];
                        Oa[dblk] = __builtin_amdgcn_mfma_f32_16x16x32_f16(pa, vb, Oa[dblk], 0, 0, 0);
                    }
                    __builtin_amdgcn_s_setprio(0);
                }
            }

            // ---- issue global loads for tile t+2 (regs now free) ----
            if (t + 2 < t1) LOADT(t + 2);
            if (more) __syncthreads();
        }
    }

    // ---- reduce deferred l across the 16 key-lanes ----
    float lrun[4];
#pragma unroll
    for (int r = 0; r < 4; ++r) {
        float v = lpart[r];
        v += __shfl_xor(v, 1);
        v += __shfl_xor(v, 2);
        v += __shfl_xor(v, 4);
        v += __shfl_xor(v, 8);
        lrun[r] = v;
    }

    // ---- epilogue ----
    if (NS == 1) {
#pragma unroll
        for (int r = 0; r < 4; ++r) {
            const int qrow = qrow0 + g * 4 + r;
            float* dst = Og + (size_t)(bb * SS + qrow) * DD + c_;
            const float inv = (lrun[r] > 0.f) ? 1.0f / lrun[r] : 0.f;
#pragma unroll
            for (int dblk = 0; dblk < 8; ++dblk)
                dst[dblk * 16] = Oa[dblk][r] * inv;
        }
    } else {
        // unnormalized f16 partial + (m, l)
        f16*    od  = Opf + (size_t)sg * SEG;
        float2* mld = mlb + (size_t)sg * BB * SS;
#pragma unroll
        for (int r = 0; r < 4; ++r) {
            const int qrow = qrow0 + g * 4 + r;
            f16* dst = od + (size_t)(bb * SS + qrow) * DD + c_;
#pragma unroll
            for (int dblk = 0; dblk < 8; ++dblk)
                dst[dblk * 16] = (f16)Oa[dblk][r];
            if (c_ == 0) mld[bb * SS + qrow] = make_float2(mrun[r], lrun[r]);
        }
    }
}

// ---------------------------------------------------------------------------
// Merge NS KV-split f16 partials: out = (sum Oi*ei) / (sum li*ei)
// Each thread handles 8 contiguous d-elements of one row.
// ---------------------------------------------------------------------------
template <int NS>
__global__ __launch_bounds__(256)
void merge_kernel(float* __restrict__ out, const f16* __restrict__ Opf,
                  const float2* __restrict__ mlb)
{
    const int idx = blockIdx.x * 256 + threadIdx.x;  // 8-elem units
    const int row = idx >> 4;                        // 16 units per row
    float2 ml[NS];
#pragma unroll
    for (int i = 0; i < NS; ++i) ml[i] = mlb[(size_t)i * BB * SS + row];
    float mm = ml[0].x;
#pragma unroll
    for (int i = 1; i < NS; ++i) mm = fmaxf(mm, ml[i].x);
    float e[NS], den = 0.f;
#pragma unroll
    for (int i = 0; i < NS; ++i) {
        e[i] = fast_exp2(ml[i].x - mm);
        den += ml[i].y * e[i];
    }
    const float inv = 1.0f / den;

    float acc[8] = {0.f, 0.f, 0.f, 0.f, 0.f, 0.f, 0.f, 0.f};
#pragma unroll
    for (int i = 0; i < NS; ++i) {
        f16x8 v = *(const f16x8*)(Opf + (size_t)i * SEG + (size_t)idx * 8);
#pragma unroll
        for (int j = 0; j < 8; ++j) acc[j] += (float)v[j] * e[i];
    }
    float4 o0, o1;
    o0.x = acc[0] * inv; o0.y = acc[1] * inv; o0.z = acc[2] * inv; o0.w = acc[3] * inv;
    o1.x = acc[4] * inv; o1.y = acc[5] * inv; o1.z = acc[6] * inv; o1.w = acc[7] * inv;
    float4* dst = (float4*)(out + (size_t)idx * 8);
    dst[0] = o0;
    dst[1] = o1;
}

extern "C" void kernel_launch(void* const* d_in, const int* in_sizes, int n_in,
                              void* d_out, int out_size, void* d_ws, size_t ws_size,
                              hipStream_t stream)
{
    const float* Q = (const float*)d_in[0];
    const float* K = (const float*)d_in[1];
    const float* V = (const float*)d_in[2];
    float* out = (float*)d_out;

    const size_t OPB = SEG * sizeof(f16);                 // 4 MB per segment
    const size_t MLB = (size_t)BB * SS * sizeof(float2);  // 128 KB per segment
    const int mergeGrid = (int)(SEG / 8 / 256);           // 1024

    const size_t need4 = 4 * OPB + 4 * MLB;

    if (ws_size >= need4) {
        f16*    Opf = (f16*)d_ws;
        float2* mlb = (float2*)((char*)d_ws + 4 * OPB);
        hipLaunchKernelGGL((attn_fwd<4>), dim3(8 * 16 * 4), dim3(512), 0, stream,
                           Q, K, V, out, Opf, mlb);
        hipLaunchKernelGGL((merge_kernel<4>), dim3(mergeGrid), dim3(256), 0, stream,
                           out, Opf, mlb);
    } else {
        hipLaunchKernelGGL((attn_fwd<1>), dim3(8 * 16), dim3(512), 0, stream,
                           Q, K, V, out, (f16*)nullptr, (float2*)nullptr);
    }
}

// Round 10
// 103.344 us; speedup vs baseline: 1.7278x; 1.0019x over previous
//
#include <hip/hip_runtime.h>

#define BB 8
#define SS 2048
#define DD 128
#define SEG ((size_t)BB * SS * DD)   // elements per partial segment

typedef _Float16 f16;
typedef _Float16 f16x2 __attribute__((ext_vector_type(2)));
typedef __fp16 h16x2 __attribute__((ext_vector_type(2)));
typedef _Float16 f16x8 __attribute__((ext_vector_type(8)));
typedef float f32x4 __attribute__((ext_vector_type(4)));
typedef int i32x4 __attribute__((ext_vector_type(4)));

// Vt LDS swizzle: spreads banks for BOTH staging writes and PV reads.
#define SWV(d) ((((d) & 7) ^ (((d) >> 3) & 7)) << 3)

#define DEFER_THR 4.0f   // exp2-domain defer-max threshold: P <= 16, f16-safe

static __device__ __forceinline__ float fast_exp2(float x) {
#if __has_builtin(__builtin_amdgcn_exp2f)
    return __builtin_amdgcn_exp2f(x);
#else
    return exp2f(x);
#endif
}

static __device__ __forceinline__ f16x2 cvt_pk(float a, float b) {
    h16x2 r = __builtin_amdgcn_cvt_pkrtz(a, b);
    return __builtin_bit_cast(f16x2, r);
}

static __device__ __forceinline__ int cvt_pk_i(float a, float b) {
    return __builtin_bit_cast(int, cvt_pk(a, b));
}

// pack 4 f32 -> 4 f16 (RTZ) as uint2 for one b64 LDS write
static __device__ __forceinline__ uint2 pack4(f32x4 v) {
    uint2 u;
    u.x = (unsigned)cvt_pk_i(v[0], v[1]);
    u.y = (unsigned)cvt_pk_i(v[2], v[3]);
    return u;
}

// ---------------------------------------------------------------------------
// Flash attention forward, causal. f16 MFMA 16x16x32, fp32 softmax/accum.
// SWAPPED-OPERAND structure: QK^T computed as S^T = mfma(K,Q) so each lane
// holds the 16 scores of ONE q-row (col = lane&15) -> softmax is in-register
// (row max = 15 fmax + 2 shuffles; l is a per-lane scalar, reduced once at
// the end). PV computed as O^T = mfma(V^T, P^T); the P^T B-fragment is built
// by 8 pull-shuffles + 4 selects per ks (src lanes loop-invariant), so there
// is NO P LDS buffer at all.
// 256 threads = 4 waves; wave owns 16 q-rows (QBLK=64). NS-way KV split,
// f16 partials + merge. Double-buffered K/V LDS, one barrier per tile.
// K  LDS: [2][64][128], el = row*128 + (col ^ ((row&7)<<3))
// Vt LDS: [2][128][64], el = d*64   + (key ^ SWV(d))
// ---------------------------------------------------------------------------
template <int NS>
__global__ __launch_bounds__(256, 2)
void attn_fwd(const float* __restrict__ Qg, const float* __restrict__ Kg,
              const float* __restrict__ Vg, float* __restrict__ Og,
              f16* __restrict__ Opf, float2* __restrict__ mlb)
{
    __shared__ __align__(16) f16 Kl[2][64 * 128];
    __shared__ __align__(16) f16 Vt[2][128 * 64];

    const int tid  = threadIdx.x;
    const int lane = tid & 63;
    const int w    = tid >> 6;
    const int c_   = lane & 15;   // this lane's q-row (and d index in PV A)
    const int g    = lane >> 4;

    // block decode: batch -> XCD; qb descending (LPT); split segment
    const int L   = blockIdx.x;
    const int bb  = L & 7;
    const int rem = L >> 3;
    const int qb  = 31 - (rem / NS);
    const int sg  = rem % NS;
    const int T   = qb + 1;
    const int t0  = (T * sg) / NS;
    const int t1  = (T * (sg + 1)) / NS;

    const int qrow0 = qb * 64 + w * 16;
    const int qi    = qrow0 + c_;          // this lane's q-row

    // exchange source lanes (loop-invariant)
    const int srcA = c_ + 32 * (g & 1);    // holds keys j=0..3 of my B-frag
    const int srcB = srcA + 16;            // holds keys j=4..7
    const int selH = g >> 1;               // 1 -> use nb=2ks+1 fetches

    // Q fragments, pre-scaled by 1/sqrt(D) * log2(e)
    const float qs = 0.08838834764831845f * 1.4426950408889634f;
    f16x8 qf[4];
    {
        const float* qp = Qg + (size_t)(bb * SS + qi) * DD;
#pragma unroll
        for (int kk = 0; kk < 4; ++kk) {
            const int d0 = kk * 32 + g * 8;
            f32x4 a = *(const f32x4*)(qp + d0);
            f32x4 b = *(const f32x4*)(qp + d0 + 4);
            f16x8 q;
#pragma unroll
            for (int i = 0; i < 4; ++i) {
                q[i]     = (f16)(a[i] * qs);
                q[i + 4] = (f16)(b[i] * qs);
            }
            qf[kk] = q;
        }
    }

    f32x4 Oa[8];   // O^T: Oa[dblk][r] = O[q-row c_][d = dblk*16 + g*4 + r]
#pragma unroll
    for (int i = 0; i < 8; ++i) Oa[i] = (f32x4){0.f, 0.f, 0.f, 0.f};
    float mrun  = -1e30f;   // per-lane running max (row c_)
    float lpart = 0.f;      // per-lane partial l (this lane's 16 keys/tile)

    // staging thread mappings
    const int krow = tid >> 5;      // K: row = krow + 8j
    const int kc4  = tid & 31;      // K: col quad
    const int vkg  = tid >> 5;      // V: key group (8 keys)
    const int vq   = tid & 31;      // V: d quad (d = vq*4 + dd)

    f32x4 kreg[8], vreg[8];

#define LOADT(tt)                                                              \
    {                                                                          \
        const size_t gb = (size_t)(bb * SS + (tt) * 64) * DD;                  \
        _Pragma("unroll")                                                      \
        for (int j = 0; j < 8; ++j)                                            \
            kreg[j] = *(const f32x4*)(Kg + gb + (krow + 8 * j) * DD + kc4 * 4);\
        _Pragma("unroll")                                                      \
        for (int i = 0; i < 8; ++i)                                            \
            vreg[i] = *(const f32x4*)(Vg + gb + (vkg * 8 + i) * DD + vq * 4);  \
    }

#define STAGE_K(pb_)                                                           \
    {                                                                          \
        _Pragma("unroll")                                                      \
        for (int j = 0; j < 8; ++j) {                                          \
            const int row = krow + 8 * j;                                      \
            const int el  = row * 128 + ((kc4 * 4) ^ ((row & 7) << 3));        \
            *(uint2*)&Kl[pb_][el] = pack4(kreg[j]);                            \
        }                                                                      \
    }

#define STAGE_V(pb_)                                                           \
    {                                                                          \
        _Pragma("unroll")                                                      \
        for (int dd = 0; dd < 4; ++dd) {                                       \
            const int d  = vq * 4 + dd;                                        \
            const int sw = SWV(d);                                             \
            _Pragma("unroll")                                                  \
            for (int h = 0; h < 2; ++h) {                                      \
                f32x4 vv = {vreg[4 * h + 0][dd], vreg[4 * h + 1][dd],          \
                            vreg[4 * h + 2][dd], vreg[4 * h + 3][dd]};         \
                const int el = d * 64 + ((vkg * 8 + 4 * h) ^ sw);              \
                *(uint2*)&Vt[pb_][el] = pack4(vv);                             \
            }                                                                  \
        }                                                                      \
    }

    if (t0 < t1) {
        LOADT(t0);
        STAGE_K(t0 & 1);
        STAGE_V(t0 & 1);
        if (t0 + 1 < t1) LOADT(t0 + 1);
        __syncthreads();

        for (int t = t0; t < t1; ++t) {
            const int pb = t & 1;
            const bool more = (t + 1 < t1);
            const int kbase = t * 64;

            // ---- QK^T swapped: s4[nb][r] = S[q-row c_][key kbase+nb*16+g*4+r]
            f32x4 s4[4];
            __builtin_amdgcn_s_setprio(1);
#pragma unroll
            for (int nb = 0; nb < 4; ++nb) {
                f32x4 acc = (f32x4){0.f, 0.f, 0.f, 0.f};
                const int row = c_ + nb * 16;
                const int sw  = (row & 7) << 3;
#pragma unroll
                for (int kk = 0; kk < 4; ++kk) {
                    f16x8 kb = *(const f16x8*)&Kl[pb][row * 128 + ((kk * 32 + g * 8) ^ sw)];
                    acc = __builtin_amdgcn_mfma_f32_16x16x32_f16(kb, qf[kk], acc, 0, 0, 0);
                }
                s4[nb] = acc;
            }
            __builtin_amdgcn_s_setprio(0);

            // ---- stage K(t+1) (hides under softmax) ----
            if (more) STAGE_K(pb ^ 1);

            // ---- causal mask (diagonal tile only) ----
            if (t == qb) {
#pragma unroll
                for (int nb = 0; nb < 4; ++nb)
#pragma unroll
                    for (int r = 0; r < 4; ++r) {
                        const int kj = kbase + nb * 16 + g * 4 + r;
                        if (kj > qi) s4[nb][r] = -1e30f;
                    }
            }

            // ---- in-register softmax for row c_ ----
            float pm = -1e30f;
#pragma unroll
            for (int nb = 0; nb < 4; ++nb) {
                f32x4 v = s4[nb];
                pm = fmaxf(pm, fmaxf(fmaxf(v[0], v[1]), fmaxf(v[2], v[3])));
            }
            pm = fmaxf(pm, __shfl_xor(pm, 16));
            pm = fmaxf(pm, __shfl_xor(pm, 32));

            if (!__all(pm - mrun <= DEFER_THR)) {
                float sc;
                if (pm - mrun <= DEFER_THR) {
                    sc = 1.0f;
                } else {
                    sc = fast_exp2(mrun - pm);
                    mrun = pm;
                }
                lpart *= sc;
#pragma unroll
                for (int dblk = 0; dblk < 8; ++dblk) {
                    Oa[dblk][0] *= sc; Oa[dblk][1] *= sc;
                    Oa[dblk][2] *= sc; Oa[dblk][3] *= sc;
                }
            }

            // ---- P = exp2(S - m), pack f16 pairs in-register ----
            int ph_lo[4], ph_hi[4];
#pragma unroll
            for (int nb = 0; nb < 4; ++nb) {
                float p0 = fast_exp2(s4[nb][0] - mrun);
                float p1 = fast_exp2(s4[nb][1] - mrun);
                float p2 = fast_exp2(s4[nb][2] - mrun);
                float p3 = fast_exp2(s4[nb][3] - mrun);
                lpart += (p0 + p1) + (p2 + p3);
                ph_lo[nb] = cvt_pk_i(p0, p1);
                ph_hi[nb] = cvt_pk_i(p2, p3);
            }

            // ---- stage V(t+1) (hides under exchange/PV) ----
            if (more) STAGE_V(pb ^ 1);

            // ---- PV swapped: O^T += mfma(V^T, P^T) ----
#pragma unroll
            for (int ks = 0; ks < 2; ++ks) {
                // build B-frag: elem j = P[key ks*32+g*8+j][row c_]
                const int lo1L = __shfl(ph_lo[2 * ks + 0], srcA);
                const int hi1L = __shfl(ph_hi[2 * ks + 0], srcA);
                const int lo2L = __shfl(ph_lo[2 * ks + 0], srcB);
                const int hi2L = __shfl(ph_hi[2 * ks + 0], srcB);
                const int lo1H = __shfl(ph_lo[2 * ks + 1], srcA);
                const int hi1H = __shfl(ph_hi[2 * ks + 1], srcA);
                const int lo2H = __shfl(ph_lo[2 * ks + 1], srcB);
                const int hi2H = __shfl(ph_hi[2 * ks + 1], srcB);
                i32x4 bw;
                bw[0] = selH ? lo1H : lo1L;
                bw[1] = selH ? hi1H : hi1L;
                bw[2] = selH ? lo2H : lo2L;
                bw[3] = selH ? hi2H : hi2L;
                const f16x8 pbfrag = __builtin_bit_cast(f16x8, bw);

                __builtin_amdgcn_s_setprio(1);
#pragma unroll
                for (int dblk = 0; dblk < 8; ++dblk) {
                    const int d  = dblk * 16 + c_;
                    f16x8 vb = *(const f16x8*)&Vt[pb][d * 64 + ((ks * 32 + g * 8) ^ SWV(d))];
                    Oa[dblk] = __builtin_amdgcn_mfma_f32_16x16x32_f16(vb, pbfrag, Oa[dblk], 0, 0, 0);
                }
                __builtin_amdgcn_s_setprio(0);
            }

            // ---- issue global loads for tile t+2 ----
            if (t + 2 < t1) LOADT(t + 2);
            if (more) __syncthreads();
        }
    }

    // ---- finalize l for row c_ (reduce across the 4 g-groups) ----
    float lrun = lpart;
    lrun += __shfl_xor(lrun, 16);
    lrun += __shfl_xor(lrun, 32);

    // ---- epilogue: lane holds O[row c_][d = dblk*16 + g*4 + 0..3] ----
    if (NS == 1) {
        float* dst = Og + (size_t)(bb * SS + qi) * DD + g * 4;
        const float inv = (lrun > 0.f) ? 1.0f / lrun : 0.f;
#pragma unroll
        for (int dblk = 0; dblk < 8; ++dblk) {
            float4 o;
            o.x = Oa[dblk][0] * inv; o.y = Oa[dblk][1] * inv;
            o.z = Oa[dblk][2] * inv; o.w = Oa[dblk][3] * inv;
            *(float4*)(dst + dblk * 16) = o;
        }
    } else {
        f16* od = Opf + (size_t)sg * SEG + (size_t)(bb * SS + qi) * DD + g * 4;
#pragma unroll
        for (int dblk = 0; dblk < 8; ++dblk)
            *(uint2*)(od + dblk * 16) = pack4(Oa[dblk]);
        if (g == 0)
            mlb[(size_t)sg * BB * SS + bb * SS + qi] = make_float2(mrun, lrun);
    }
}

// ---------------------------------------------------------------------------
// Merge NS KV-split f16 partials: out = (sum Oi*ei) / (sum li*ei)
// Each thread handles 8 contiguous d-elements of one row.
// ---------------------------------------------------------------------------
template <int NS>
__global__ __launch_bounds__(256)
void merge_kernel(float* __restrict__ out, const f16* __restrict__ Opf,
                  const float2* __restrict__ mlb)
{
    const int idx = blockIdx.x * 256 + threadIdx.x;  // 8-elem units
    const int row = idx >> 4;                        // 16 units per row
    float2 ml[NS];
#pragma unroll
    for (int i = 0; i < NS; ++i) ml[i] = mlb[(size_t)i * BB * SS + row];
    float mm = ml[0].x;
#pragma unroll
    for (int i = 1; i < NS; ++i) mm = fmaxf(mm, ml[i].x);
    float e[NS], den = 0.f;
#pragma unroll
    for (int i = 0; i < NS; ++i) {
        e[i] = fast_exp2(ml[i].x - mm);
        den += ml[i].y * e[i];
    }
    const float inv = 1.0f / den;

    float acc[8] = {0.f, 0.f, 0.f, 0.f, 0.f, 0.f, 0.f, 0.f};
#pragma unroll
    for (int i = 0; i < NS; ++i) {
        f16x8 v = *(const f16x8*)(Opf + (size_t)i * SEG + (size_t)idx * 8);
#pragma unroll
        for (int j = 0; j < 8; ++j) acc[j] += (float)v[j] * e[i];
    }
    float4 o0, o1;
    o0.x = acc[0] * inv; o0.y = acc[1] * inv; o0.z = acc[2] * inv; o0.w = acc[3] * inv;
    o1.x = acc[4] * inv; o1.y = acc[5] * inv; o1.z = acc[6] * inv; o1.w = acc[7] * inv;
    float4* dst = (float4*)(out + (size_t)idx * 8);
    dst[0] = o0;
    dst[1] = o1;
}

extern "C" void kernel_launch(void* const* d_in, const int* in_sizes, int n_in,
                              void* d_out, int out_size, void* d_ws, size_t ws_size,
                              hipStream_t stream)
{
    const float* Q = (const float*)d_in[0];
    const float* K = (const float*)d_in[1];
    const float* V = (const float*)d_in[2];
    float* out = (float*)d_out;

    const size_t OPB = SEG * sizeof(f16);                 // 4 MB per segment
    const size_t MLB = (size_t)BB * SS * sizeof(float2);  // 128 KB per segment
    const int mergeGrid = (int)(SEG / 8 / 256);           // 1024

    const size_t need4 = 4 * OPB + 4 * MLB;

    if (ws_size >= need4) {
        f16*    Opf = (f16*)d_ws;
        float2* mlb = (float2*)((char*)d_ws + 4 * OPB);
        hipLaunchKernelGGL((attn_fwd<4>), dim3(8 * 32 * 4), dim3(256), 0, stream,
                           Q, K, V, out, Opf, mlb);
        hipLaunchKernelGGL((merge_kernel<4>), dim3(mergeGrid), dim3(256), 0, stream,
                           out, Opf, mlb);
    } else {
        hipLaunchKernelGGL((attn_fwd<1>), dim3(8 * 32), dim3(256), 0, stream,
                           Q, K, V, out, (f16*)nullptr, (float2*)nullptr);
    }
}

// Round 11
// 100.959 us; speedup vs baseline: 1.7686x; 1.0236x over previous
//
#include <hip/hip_runtime.h>

#define BB 8
#define SS 2048
#define DD 128
#define SEG ((size_t)BB * SS * DD)   // elements per partial segment

typedef _Float16 f16;
typedef _Float16 f16x2 __attribute__((ext_vector_type(2)));
typedef __fp16 h16x2 __attribute__((ext_vector_type(2)));
typedef _Float16 f16x8 __attribute__((ext_vector_type(8)));
typedef float f32x4 __attribute__((ext_vector_type(4)));
typedef int i32x4 __attribute__((ext_vector_type(4)));

// Vt LDS swizzle: spreads banks for BOTH staging writes and PV reads.
#define SWV(d) ((((d) & 7) ^ (((d) >> 3) & 7)) << 3)

#define DEFER_THR 4.0f   // exp2-domain defer-max threshold: P <= 16, f16-safe

static __device__ __forceinline__ float fast_exp2(float x) {
#if __has_builtin(__builtin_amdgcn_exp2f)
    return __builtin_amdgcn_exp2f(x);
#else
    return exp2f(x);
#endif
}

static __device__ __forceinline__ f16x2 cvt_pk(float a, float b) {
    h16x2 r = __builtin_amdgcn_cvt_pkrtz(a, b);
    return __builtin_bit_cast(f16x2, r);
}

static __device__ __forceinline__ int cvt_pk_i(float a, float b) {
    return __builtin_bit_cast(int, cvt_pk(a, b));
}

// ---------------------------------------------------------------------------
// Flash attention forward, causal. f16 MFMA 16x16x32, fp32 softmax/accum.
// SWAPPED-OPERAND + LOGICAL-KEY-PERMUTED structure:
//   QK^T computed as S^T = mfma(K,Q); K rows are staged PERMUTED in LDS so
//   that the key in MFMA slot (nb, g, r) is u = 8g + 32(nb&1) + 4(nb>>1) + r.
//   Consequence: lane (c_,g)'s 16 scores are exactly keys [8g..8g+8) and
//   [32+8g..32+8g+8) -> the PV B-fragment for ks is the lane-local pack
//   [P(nb=ks, r0..3), P(nb=ks+2, r0..3)]. ZERO cross-lane shuffles in PV.
//   Softmax in-register (15 fmax + 2 xor-shuffles); l is per-lane scalar.
// 256 threads = 4 waves; wave owns 16 q-rows (QBLK=64). NS-way KV split,
// f16 partials + merge. Double-buffered K/V LDS, one barrier per tile.
// All staging stores are b128 (4 per thread per buffer).
// K  LDS: [2][64][128], row L(u) = (b1+2b2)*16+4*gl+rl of key u,
//         el = L*128 + (col ^ ((L&7)<<3))
// Vt LDS: [2][128][64], el = d*64 + (key ^ SWV(d))
// ---------------------------------------------------------------------------
template <int NS>
__global__ __launch_bounds__(256, 2)
void attn_fwd(const float* __restrict__ Qg, const float* __restrict__ Kg,
              const float* __restrict__ Vg, float* __restrict__ Og,
              f16* __restrict__ Opf, float2* __restrict__ mlb)
{
    __shared__ __align__(16) f16 Kl[2][64 * 128];
    __shared__ __align__(16) f16 Vt[2][128 * 64];

    const int tid  = threadIdx.x;
    const int lane = tid & 63;
    const int w    = tid >> 6;
    const int c_   = lane & 15;   // this lane's q-row (and d index in PV A)
    const int g    = lane >> 4;

    // block decode: batch -> XCD; qb descending (LPT); split segment
    const int L   = blockIdx.x;
    const int bb  = L & 7;
    const int rem = L >> 3;
    const int qb  = 31 - (rem / NS);
    const int sg  = rem % NS;
    const int T   = qb + 1;
    const int t0  = (T * sg) / NS;
    const int t1  = (T * (sg + 1)) / NS;

    const int qrow0 = qb * 64 + w * 16;
    const int qi    = qrow0 + c_;          // this lane's q-row

    // Q fragments, pre-scaled by 1/sqrt(D) * log2(e)
    const float qs = 0.08838834764831845f * 1.4426950408889634f;
    f16x8 qf[4];
    {
        const float* qp = Qg + (size_t)(bb * SS + qi) * DD;
#pragma unroll
        for (int kk = 0; kk < 4; ++kk) {
            const int d0 = kk * 32 + g * 8;
            f32x4 a = *(const f32x4*)(qp + d0);
            f32x4 b = *(const f32x4*)(qp + d0 + 4);
            f16x8 q;
#pragma unroll
            for (int i = 0; i < 4; ++i) {
                q[i]     = (f16)(a[i] * qs);
                q[i + 4] = (f16)(b[i] * qs);
            }
            qf[kk] = q;
        }
    }

    f32x4 Oa[8];   // O^T: Oa[dblk][r] = O[q-row c_][d = dblk*16 + g*4 + r]
#pragma unroll
    for (int i = 0; i < 8; ++i) Oa[i] = (f32x4){0.f, 0.f, 0.f, 0.f};
    float mrun  = -1e30f;   // per-lane running max (row c_)
    float lpart = 0.f;      // per-lane partial l

    // staging thread mappings
    const int kcg  = tid & 15;      // K: 16B col-group (8 f16), col0 = kcg*8
    const int krow = tid >> 4;      // K: row = krow + 16j (0..15)
    const int vkg  = tid >> 5;      // V: key group (8 keys)
    const int vq   = tid & 31;      // V: d quad (d = vq*4 + dd)

    f32x4 kreg[4][2], vreg[8];

#define LOADT(tt)                                                              \
    {                                                                          \
        const size_t gb = (size_t)(bb * SS + (tt) * 64) * DD;                  \
        _Pragma("unroll")                                                      \
        for (int j = 0; j < 4; ++j) {                                          \
            const float* kp = Kg + gb + (krow + 16 * j) * DD + kcg * 8;        \
            kreg[j][0] = *(const f32x4*)(kp);                                  \
            kreg[j][1] = *(const f32x4*)(kp + 4);                              \
        }                                                                      \
        _Pragma("unroll")                                                      \
        for (int i = 0; i < 8; ++i)                                            \
            vreg[i] = *(const f32x4*)(Vg + gb + (vkg * 8 + i) * DD + vq * 4);  \
    }

    // K permuted staging: key u -> LDS row Lr(u) = (b1+2b2)*16 + 4*gl + rl
#define STAGE_K(pb_)                                                           \
    {                                                                          \
        _Pragma("unroll")                                                      \
        for (int j = 0; j < 4; ++j) {                                          \
            const int u  = krow + 16 * j;                                      \
            const int Lr = (((u >> 5) & 1) + 2 * ((u >> 2) & 1)) * 16          \
                         + ((u >> 3) & 3) * 4 + (u & 3);                       \
            const int el = Lr * 128 + ((kcg * 8) ^ ((Lr & 7) << 3));           \
            uint4 u4;                                                          \
            u4.x = (unsigned)cvt_pk_i(kreg[j][0][0], kreg[j][0][1]);           \
            u4.y = (unsigned)cvt_pk_i(kreg[j][0][2], kreg[j][0][3]);           \
            u4.z = (unsigned)cvt_pk_i(kreg[j][1][0], kreg[j][1][1]);           \
            u4.w = (unsigned)cvt_pk_i(kreg[j][1][2], kreg[j][1][3]);           \
            *(uint4*)&Kl[pb_][el] = u4;                                        \
        }                                                                      \
    }

#define STAGE_V(pb_)                                                           \
    {                                                                          \
        _Pragma("unroll")                                                      \
        for (int dd = 0; dd < 4; ++dd) {                                       \
            const int d  = vq * 4 + dd;                                        \
            const int el = d * 64 + ((vkg * 8) ^ SWV(d));                      \
            uint4 u4;                                                          \
            u4.x = (unsigned)cvt_pk_i(vreg[0][dd], vreg[1][dd]);               \
            u4.y = (unsigned)cvt_pk_i(vreg[2][dd], vreg[3][dd]);               \
            u4.z = (unsigned)cvt_pk_i(vreg[4][dd], vreg[5][dd]);               \
            u4.w = (unsigned)cvt_pk_i(vreg[6][dd], vreg[7][dd]);               \
            *(uint4*)&Vt[pb_][el] = u4;                                        \
        }                                                                      \
    }

    if (t0 < t1) {
        LOADT(t0);
        STAGE_K(t0 & 1);
        STAGE_V(t0 & 1);
        if (t0 + 1 < t1) LOADT(t0 + 1);
        __syncthreads();

        for (int t = t0; t < t1; ++t) {
            const int pb = t & 1;
            const bool more = (t + 1 < t1);
            const int kbase = t * 64;

            // ---- QK^T swapped: s4[nb][r] = S[row c_][key 8g+32(nb&1)+4(nb>>1)+r]
            f32x4 s4[4];
            __builtin_amdgcn_s_setprio(1);
#pragma unroll
            for (int nb = 0; nb < 4; ++nb) {
                f32x4 acc = (f32x4){0.f, 0.f, 0.f, 0.f};
                const int row = c_ + nb * 16;
                const int sw  = (row & 7) << 3;
#pragma unroll
                for (int kk = 0; kk < 4; ++kk) {
                    f16x8 kb = *(const f16x8*)&Kl[pb][row * 128 + ((kk * 32 + g * 8) ^ sw)];
                    acc = __builtin_amdgcn_mfma_f32_16x16x32_f16(kb, qf[kk], acc, 0, 0, 0);
                }
                s4[nb] = acc;
            }
            __builtin_amdgcn_s_setprio(0);

            // ---- stage K(t+1) (hides under softmax) ----
            if (more) STAGE_K(pb ^ 1);

            // ---- causal mask (diagonal tile only), permuted key ids ----
            if (t == qb) {
#pragma unroll
                for (int nb = 0; nb < 4; ++nb)
#pragma unroll
                    for (int r = 0; r < 4; ++r) {
                        const int kj = kbase + 8 * g + 32 * (nb & 1) + 4 * (nb >> 1) + r;
                        if (kj > qi) s4[nb][r] = -1e30f;
                    }
            }

            // ---- in-register softmax for row c_ ----
            float pm = -1e30f;
#pragma unroll
            for (int nb = 0; nb < 4; ++nb) {
                f32x4 v = s4[nb];
                pm = fmaxf(pm, fmaxf(fmaxf(v[0], v[1]), fmaxf(v[2], v[3])));
            }
            pm = fmaxf(pm, __shfl_xor(pm, 16));
            pm = fmaxf(pm, __shfl_xor(pm, 32));

            if (!__all(pm - mrun <= DEFER_THR)) {
                float sc;
                if (pm - mrun <= DEFER_THR) {
                    sc = 1.0f;
                } else {
                    sc = fast_exp2(mrun - pm);
                    mrun = pm;
                }
                lpart *= sc;
#pragma unroll
                for (int dblk = 0; dblk < 8; ++dblk) {
                    Oa[dblk][0] *= sc; Oa[dblk][1] *= sc;
                    Oa[dblk][2] *= sc; Oa[dblk][3] *= sc;
                }
            }

            // ---- P = exp2(S - m), pack f16 pairs in-register ----
            int ph_lo[4], ph_hi[4];
#pragma unroll
            for (int nb = 0; nb < 4; ++nb) {
                float p0 = fast_exp2(s4[nb][0] - mrun);
                float p1 = fast_exp2(s4[nb][1] - mrun);
                float p2 = fast_exp2(s4[nb][2] - mrun);
                float p3 = fast_exp2(s4[nb][3] - mrun);
                lpart += (p0 + p1) + (p2 + p3);
                ph_lo[nb] = cvt_pk_i(p0, p1);
                ph_hi[nb] = cvt_pk_i(p2, p3);
            }

            // ---- stage V(t+1) (hides under PV) ----
            if (more) STAGE_V(pb ^ 1);

            // ---- PV swapped: O^T += mfma(V^T, P^T); B-frag is LANE-LOCAL ----
#pragma unroll
            for (int ks = 0; ks < 2; ++ks) {
                i32x4 bw;
                bw[0] = ph_lo[ks];
                bw[1] = ph_hi[ks];
                bw[2] = ph_lo[ks + 2];
                bw[3] = ph_hi[ks + 2];
                const f16x8 pbfrag = __builtin_bit_cast(f16x8, bw);

                __builtin_amdgcn_s_setprio(1);
#pragma unroll
                for (int dblk = 0; dblk < 8; ++dblk) {
                    const int d  = dblk * 16 + c_;
                    f16x8 vb = *(const f16x8*)&Vt[pb][d * 64 + ((ks * 32 + g * 8) ^ SWV(d))];
                    Oa[dblk] = __builtin_amdgcn_mfma_f32_16x16x32_f16(vb, pbfrag, Oa[dblk], 0, 0, 0);
                }
                __builtin_amdgcn_s_setprio(0);
            }

            // ---- issue global loads for tile t+2 ----
            if (t + 2 < t1) LOADT(t + 2);
            if (more) __syncthreads();
        }
    }

    // ---- finalize l for row c_ (reduce across the 4 g-groups) ----
    float lrun = lpart;
    lrun += __shfl_xor(lrun, 16);
    lrun += __shfl_xor(lrun, 32);

    // ---- epilogue: lane holds O[row c_][d = dblk*16 + g*4 + 0..3] ----
    if (NS == 1) {
        float* dst = Og + (size_t)(bb * SS + qi) * DD + g * 4;
        const float inv = (lrun > 0.f) ? 1.0f / lrun : 0.f;
#pragma unroll
        for (int dblk = 0; dblk < 8; ++dblk) {
            float4 o;
            o.x = Oa[dblk][0] * inv; o.y = Oa[dblk][1] * inv;
            o.z = Oa[dblk][2] * inv; o.w = Oa[dblk][3] * inv;
            *(float4*)(dst + dblk * 16) = o;
        }
    } else {
        f16* od = Opf + (size_t)sg * SEG + (size_t)(bb * SS + qi) * DD + g * 4;
#pragma unroll
        for (int dblk = 0; dblk < 8; ++dblk) {
            uint2 u;
            u.x = (unsigned)cvt_pk_i(Oa[dblk][0], Oa[dblk][1]);
            u.y = (unsigned)cvt_pk_i(Oa[dblk][2], Oa[dblk][3]);
            *(uint2*)(od + dblk * 16) = u;
        }
        if (g == 0)
            mlb[(size_t)sg * BB * SS + bb * SS + qi] = make_float2(mrun, lrun);
    }
}

// ---------------------------------------------------------------------------
// Merge NS KV-split f16 partials: out = (sum Oi*ei) / (sum li*ei)
// Each thread handles 8 contiguous d-elements of one row.
// ---------------------------------------------------------------------------
template <int NS>
__global__ __launch_bounds__(256)
void merge_kernel(float* __restrict__ out, const f16* __restrict__ Opf,
                  const float2* __restrict__ mlb)
{
    const int idx = blockIdx.x * 256 + threadIdx.x;  // 8-elem units
    const int row = idx >> 4;                        // 16 units per row
    float2 ml[NS];
#pragma unroll
    for (int i = 0; i < NS; ++i) ml[i] = mlb[(size_t)i * BB * SS + row];
    float mm = ml[0].x;
#pragma unroll
    for (int i = 1; i < NS; ++i) mm = fmaxf(mm, ml[i].x);
    float e[NS], den = 0.f;
#pragma unroll
    for (int i = 0; i < NS; ++i) {
        e[i] = fast_exp2(ml[i].x - mm);
        den += ml[i].y * e[i];
    }
    const float inv = 1.0f / den;

    float acc[8] = {0.f, 0.f, 0.f, 0.f, 0.f, 0.f, 0.f, 0.f};
#pragma unroll
    for (int i = 0; i < NS; ++i) {
        f16x8 v = *(const f16x8*)(Opf + (size_t)i * SEG + (size_t)idx * 8);
#pragma unroll
        for (int j = 0; j < 8; ++j) acc[j] += (float)v[j] * e[i];
    }
    float4 o0, o1;
    o0.x = acc[0] * inv; o0.y = acc[1] * inv; o0.z = acc[2] * inv; o0.w = acc[3] * inv;
    o1.x = acc[4] * inv; o1.y = acc[5] * inv; o1.z = acc[6] * inv; o1.w = acc[7] * inv;
    float4* dst = (float4*)(out + (size_t)idx * 8);
    dst[0] = o0;
    dst[1] = o1;
}

extern "C" void kernel_launch(void* const* d_in, const int* in_sizes, int n_in,
                              void* d_out, int out_size, void* d_ws, size_t ws_size,
                              hipStream_t stream)
{
    const float* Q = (const float*)d_in[0];
    const float* K = (const float*)d_in[1];
    const float* V = (const float*)d_in[2];
    float* out = (float*)d_out;

    const size_t OPB = SEG * sizeof(f16);                 // 4 MB per segment
    const size_t MLB = (size_t)BB * SS * sizeof(float2);  // 128 KB per segment
    const int mergeGrid = (int)(SEG / 8 / 256);           // 1024

    const size_t need4 = 4 * OPB + 4 * MLB;

    if (ws_size >= need4) {
        f16*    Opf = (f16*)d_ws;
        float2* mlb = (float2*)((char*)d_ws + 4 * OPB);
        hipLaunchKernelGGL((attn_fwd<4>), dim3(8 * 32 * 4), dim3(256), 0, stream,
                           Q, K, V, out, Opf, mlb);
        hipLaunchKernelGGL((merge_kernel<4>), dim3(mergeGrid), dim3(256), 0, stream,
                           out, Opf, mlb);
    } else {
        hipLaunchKernelGGL((attn_fwd<1>), dim3(8 * 32), dim3(256), 0, stream,
                           Q, K, V, out, (f16*)nullptr, (float2*)nullptr);
    }
}